// Round 2
// baseline (500.849 us; speedup 1.0000x reference)
//
#include <hip/hip_runtime.h>
#include <stdint.h>

// KmeansAudioQuantizer on MI355X (gfx950)
// B=8, L=1024, C=1024, N=5000.  M = B*L = 8192 queries.
//
// Round 2: fuse min-reduce + candidate collection into the GEMM epilogue.
// No dist matrix (was 168 MB write + 168 MB read).
//   1) init_state: per-row packed argmin -> ~0, candidate counters -> 0, loss -> 0
//   2) convert_z:  z (f32) -> bf16
//   3) prep_cb:    codebook -> bf16 (padded to 5120 rows) + exact f32 c2[n]
//   4) gemm_score: score = c2[n] - 2*z.c (bf16 MFMA); epilogue does per-row
//      lex-min (shfl_xor) -> atomicMin(packed u64), and appends margin
//      candidates (score <= min(waveRowMin, globalMinSoFar)+8) to cand[m][.]
//   5) finalize:   filter candidates vs final gmin+8, exact f64 rescore
//      (~2 rows/query), masked gather -> out_q, out_i

#define M_TOTAL  8192
#define K_DIM    1024
#define N_REAL   5000
#define N_PAD    5120
#define CAND_CAP 256
#define MARGIN   8.0f

typedef __attribute__((ext_vector_type(8))) short bf16x8;
typedef __attribute__((ext_vector_type(4))) float f32x4;

__device__ __forceinline__ ushort f2bf(float x) {
  union { float f; uint32_t u; } v; v.f = x;
  uint32_t r = v.u + 0x7FFFu + ((v.u >> 16) & 1u);   // round-to-nearest-even
  return (ushort)(r >> 16);
}

__device__ __forceinline__ void async16(void* lds, const void* g) {
  __builtin_amdgcn_global_load_lds(
      (const __attribute__((address_space(1))) void*)g,
      (__attribute__((address_space(3))) void*)lds, 16, 0, 0);
}

// monotone float<->uint32 encode (total order matches float order)
__device__ __forceinline__ uint32_t fenc(float f) {
  union { float f; uint32_t u; } v; v.f = f;
  return v.u ^ ((v.u >> 31) ? 0xFFFFFFFFu : 0x80000000u);
}
__device__ __forceinline__ float fdec(uint32_t e) {
  uint32_t u = e ^ ((e & 0x80000000u) ? 0x80000000u : 0xFFFFFFFFu);
  union { uint32_t u; float f; } v; v.u = u; return v.f;
}

// ---------------------------------------------------------------- prep kernels

__global__ __launch_bounds__(256) void init_state(unsigned long long* __restrict__ gmin,
                                                  int* __restrict__ ccnt,
                                                  float* __restrict__ out_loss) {
  int i = blockIdx.x * blockDim.x + threadIdx.x;
  if (i < M_TOTAL) { gmin[i] = ~0ull; ccnt[i] = 0; }
  if (i == 0) out_loss[0] = 0.0f;
}

__global__ __launch_bounds__(256) void convert_z(const float4* __restrict__ z4,
                                                 ushort* __restrict__ zb, int n4) {
  int i = blockIdx.x * blockDim.x + threadIdx.x;
  int stride = gridDim.x * blockDim.x;
  for (; i < n4; i += stride) {
    float4 v = z4[i];
    ushort4 u;
    u.x = f2bf(v.x); u.y = f2bf(v.y); u.z = f2bf(v.z); u.w = f2bf(v.w);
    *(ushort4*)&zb[(size_t)i * 4] = u;
  }
}

__global__ __launch_bounds__(256) void prep_cb(const float* __restrict__ cb,
                                               ushort* __restrict__ cbb,
                                               float* __restrict__ c2) {
  __shared__ float sred[4];
  const int row = blockIdx.x;       // 0..5119
  const int tid = threadIdx.x;
  if (row >= N_REAL) {              // zero pad rows so GEMM reads are benign
    ushort4 zz; zz.x = zz.y = zz.z = zz.w = 0;
    *(ushort4*)&cbb[(size_t)row * K_DIM + tid * 4] = zz;
    if (tid == 0) c2[row] = 0.f;
    return;
  }
  float4 v = ((const float4*)(cb + (size_t)row * K_DIM))[tid];
  ushort4 u;
  u.x = f2bf(v.x); u.y = f2bf(v.y); u.z = f2bf(v.z); u.w = f2bf(v.w);
  *(ushort4*)&cbb[(size_t)row * K_DIM + tid * 4] = u;
  float s = v.x * v.x + v.y * v.y + v.z * v.z + v.w * v.w;
  #pragma unroll
  for (int off = 32; off; off >>= 1) s += __shfl_down(s, off);
  int wv = tid >> 6, ln = tid & 63;
  if (ln == 0) sred[wv] = s;
  __syncthreads();
  if (tid == 0) c2[row] = sred[0] + sred[1] + sred[2] + sred[3];
}

// ------------------------------------------------- GEMM + fused argmin/collect
// 128x128 tile, BK=64, 4 waves (2x2 of 64x64), 16x16x32 bf16 MFMA.
// A = z_bf16 [8192][1024], B = cb_bf16 [5120][1024] (both K-major -> C = A.B^T)

__global__ __launch_bounds__(256) void gemm_score(const ushort* __restrict__ A,
                                                  const ushort* __restrict__ Bm,
                                                  const float* __restrict__ c2,
                                                  unsigned long long* __restrict__ gmin,
                                                  int* __restrict__ ccnt,
                                                  unsigned long long* __restrict__ cand) {
  __shared__ ushort sA[128 * 64];
  __shared__ ushort sB[128 * 64];
  const int tid  = threadIdx.x;
  const int wave = tid >> 6, lane = tid & 63;
  const int wm = wave >> 1, wn = wave & 1;
  const int tM = blockIdx.y * 128;             // A row (full M, no chunking)
  const int tN = blockIdx.x * 128;             // codebook row

  f32x4 acc[4][4];
  #pragma unroll
  for (int i = 0; i < 4; ++i)
    #pragma unroll
    for (int j = 0; j < 4; ++j)
      acc[i][j] = (f32x4)0.f;

  char* sAb = (char*)sA;
  char* sBb = (char*)sB;
  const int o = tid * 16;                      // byte offset within 16KB tile

  for (int k0 = 0; k0 < K_DIM; k0 += 64) {
    __syncthreads();                           // protect LDS from prev readers
    #pragma unroll
    for (int it = 0; it < 4; ++it) {
      int ob = o + it * 4096;                  // 0..16383
      int r  = ob >> 7;                        // tile row (128B per row)
      int cbyte = ob & 127;
      const char* ga = (const char*)A + ((size_t)(tM + r) * K_DIM + k0) * 2 + cbyte;
      async16(sAb + ob, ga);
      const char* gb = (const char*)Bm + ((size_t)(tN + r) * K_DIM + k0) * 2 + cbyte;
      async16(sBb + ob, gb);
    }
    __syncthreads();                           // drains vmcnt before barrier
    #pragma unroll
    for (int kk = 0; kk < 2; ++kk) {
      bf16x8 af[4], bfr[4];
      const int kcol = kk * 32 + (lane >> 4) * 8;
      #pragma unroll
      for (int f = 0; f < 4; ++f) {
        int ra = wm * 64 + f * 16 + (lane & 15);
        af[f]  = *(const bf16x8*)&sA[ra * 64 + kcol];
        int rb = wn * 64 + f * 16 + (lane & 15);
        bfr[f] = *(const bf16x8*)&sB[rb * 64 + kcol];
      }
      #pragma unroll
      for (int i = 0; i < 4; ++i)
        #pragma unroll
        for (int j = 0; j < 4; ++j)
          acc[i][j] = __builtin_amdgcn_mfma_f32_16x16x32_bf16(af[i], bfr[j], acc[i][j], 0, 0, 0);
    }
  }

  // ---- fused epilogue: per-row lex-min + margin candidate collection ----
  // C/D layout: row = i*16 + (lane>>4)*4 + r (within wave tile), col = j*16 + (lane&15)
  const int cl = lane & 15, rg = lane >> 4;
  int   ncol[4];
  float c2v[4];
  #pragma unroll
  for (int j = 0; j < 4; ++j) {
    ncol[j] = tN + wn * 64 + j * 16 + cl;
    c2v[j]  = (ncol[j] < N_REAL) ? c2[ncol[j]] : 0.f;
  }

  #pragma unroll
  for (int i = 0; i < 4; ++i) {
    #pragma unroll
    for (int r = 0; r < 4; ++r) {
      const int m = tM + wm * 64 + i * 16 + rg * 4 + r;
      float sc[4];
      float bv = 3.4e38f; int bc = 0x7fffffff;
      #pragma unroll
      for (int j = 0; j < 4; ++j) {
        sc[j] = (ncol[j] < N_REAL) ? (c2v[j] - 2.0f * acc[i][j][r]) : 3.4e38f;
        if (sc[j] < bv || (sc[j] == bv && ncol[j] < bc)) { bv = sc[j]; bc = ncol[j]; }
      }
      // lex-min across the 16 lanes sharing rg (xor stays within the group)
      #pragma unroll
      for (int off = 1; off < 16; off <<= 1) {
        float ov = __shfl_xor(bv, off);
        int   oc = __shfl_xor(bc, off);
        if (ov < bv || (ov == bv && oc < bc)) { bv = ov; bc = oc; }
      }
      // tighten threshold with the global min seen so far (stale value is
      // >= final gmin, so the filter is only ever looser than needed: safe)
      unsigned long long cur = gmin[m];
      float gv = 3.4e38f;
      if (cur != ~0ull) gv = fdec((uint32_t)(cur >> 32));
      const float thr = fminf(bv, gv) + MARGIN;
      #pragma unroll
      for (int j = 0; j < 4; ++j) {
        if (ncol[j] < N_REAL && sc[j] <= thr) {
          int p = atomicAdd(&ccnt[m], 1);
          if (p < CAND_CAP) {
            union { float f; uint32_t u; } s; s.f = sc[j];
            cand[(size_t)m * CAND_CAP + p] = ((unsigned long long)(uint32_t)ncol[j] << 32) | s.u;
          }
        }
      }
      if (cl == 0 && bc != 0x7fffffff) {
        unsigned long long pk = ((unsigned long long)fenc(bv) << 32) | (uint32_t)bc;
        atomicMin(&gmin[m], pk);
      }
    }
  }
}

// ------------------------------------------------------- finalize (per query)
// Filter candidates vs final gmin+MARGIN, exact f64 rescore, masked gather.

__global__ __launch_bounds__(256) void finalize(const unsigned long long* __restrict__ gmin,
                                                const int* __restrict__ ccnt,
                                                const unsigned long long* __restrict__ cand,
                                                const float* __restrict__ z,
                                                const float* __restrict__ cb,
                                                const int* __restrict__ mask,
                                                float* __restrict__ out_q,
                                                float* __restrict__ out_i) {
  __shared__ int scand[CAND_CAP];
  __shared__ int scnt;
  __shared__ double sdv[4];
  __shared__ double sbestd;
  __shared__ int    sbesti;

  const int tid = threadIdx.x;
  const int m   = blockIdx.x;

  const unsigned long long g = gmin[m];
  const float gv   = fdec((uint32_t)(g >> 32));
  const int   gcol = (int)(g & 0xFFFFFFFFu);
  int cnt = ccnt[m]; if (cnt > CAND_CAP) cnt = CAND_CAP;

  if (tid == 0) { scand[0] = gcol; scnt = 1; }
  __syncthreads();

  const float thr = gv + MARGIN;
  for (int i = tid; i < cnt; i += 256) {
    unsigned long long e = cand[(size_t)m * CAND_CAP + i];
    union { uint32_t u; float f; } s; s.u = (uint32_t)(e & 0xFFFFFFFFu);
    int col = (int)(e >> 32);
    if (col != gcol && s.f <= thr) {
      int p = atomicAdd(&scnt, 1);
      if (p < CAND_CAP) scand[p] = col;
    }
  }
  __syncthreads();
  int nc = scnt; if (nc > CAND_CAP) nc = CAND_CAP;

  if (tid == 0) { sbestd = 1e300; sbesti = 0x7fffffff; }
  __syncthreads();

  const int wv = tid >> 6, ln = tid & 63;
  const float* zr = z + (size_t)m * K_DIM;
  const float4 zv = ((const float4*)zr)[tid];

  for (int c = 0; c < nc; ++c) {
    const int n = scand[c];
    float4 cv = ((const float4*)(cb + (size_t)n * K_DIM))[tid];
    double lsum = (double)cv.x * ((double)cv.x - 2.0 * (double)zv.x)
                + (double)cv.y * ((double)cv.y - 2.0 * (double)zv.y)
                + (double)cv.z * ((double)cv.z - 2.0 * (double)zv.z)
                + (double)cv.w * ((double)cv.w - 2.0 * (double)zv.w);
    #pragma unroll
    for (int off = 32; off; off >>= 1) lsum += __shfl_down(lsum, off);
    if (ln == 0) sdv[wv] = lsum;
    __syncthreads();
    if (tid == 0) {
      double s = sdv[0] + sdv[1] + sdv[2] + sdv[3];
      if (s < sbestd || (s == sbestd && n < sbesti)) { sbestd = s; sbesti = n; }
    }
    __syncthreads();
  }

  const int bidx = sbesti;
  if (tid == 0) out_i[m] = (float)bidx;
  const int mk = mask[m];
  float4 qz; qz.x = qz.y = qz.z = qz.w = 0.f;
  float4 src = ((const float4*)(cb + (size_t)bidx * K_DIM))[tid];
  ((float4*)(out_q + (size_t)m * K_DIM))[tid] = mk ? src : qz;
}

// -------------------------------------------------------------------- launcher

extern "C" void kernel_launch(void* const* d_in, const int* in_sizes, int n_in,
                              void* d_out, int out_size, void* d_ws, size_t ws_size,
                              hipStream_t stream) {
  const float* z    = (const float*)d_in[0];
  const int*   mask = (const int*)d_in[1];
  const float* cb   = (const float*)d_in[2];

  float* out      = (float*)d_out;
  float* out_q    = out;                                   // [8192][1024]
  float* out_i    = out + (size_t)M_TOTAL * K_DIM;         // [8192] (as float)
  float* out_loss = out_i + M_TOTAL;                       // [1]

  char* ws = (char*)d_ws;
  ushort*             zb   = (ushort*)(ws);                        // 16,777,216 B
  ushort*             cbb  = (ushort*)(ws + 16777216);             // 10,485,760 B
  float*              c2   = (float*)(ws + 27262976);              //     20,480 B
  unsigned long long* gmin = (unsigned long long*)(ws + 27283456); //     65,536 B
  int*                ccnt = (int*)(ws + 27348992);                //     32,768 B
  unsigned long long* cand = (unsigned long long*)(ws + 27381760); // 16,777,216 B

  init_state<<<32, 256, 0, stream>>>(gmin, ccnt, out_loss);
  convert_z<<<2048, 256, 0, stream>>>((const float4*)z, zb, (M_TOTAL * K_DIM) / 4);
  prep_cb<<<N_PAD, 256, 0, stream>>>(cb, cbb, c2);

  dim3 g(N_PAD / 128, M_TOTAL / 128);
  gemm_score<<<g, 256, 0, stream>>>(zb, cbb, c2, gmin, ccnt, cand);
  finalize<<<M_TOTAL, 256, 0, stream>>>(gmin, ccnt, cand, z, cb, mask, out_q, out_i);
}

// Round 5
// 312.189 us; speedup vs baseline: 1.6043x; 1.6043x over previous
//
#include <hip/hip_runtime.h>
#include <stdint.h>

// KmeansAudioQuantizer on MI355X (gfx950)
// B=8, L=1024, C=1024, N=5000.  M = B*L = 8192 queries.
//
// Round 3 kernel, resubmitted unchanged (two GPU-acquisition timeouts; never
// measured): fused epilogue with ZERO global atomics (R2's 280us regression
// was cross-XCD atomic serialization on shared cachelines).
// Per (row, 128-col slice): block-local lex-min + margin candidates (LDS
// atomics only), written as 6 packed u64 slots -> cand[m][40][6].
// Correctness: any col within global_min+MARGIN is within its own slice's
// min+MARGIN (slice_min >= global_min), so per-slice collection is a superset.
//   1) convert_z: z (f32) -> bf16
//   2) prep_cb:   codebook -> bf16 (padded to 5120 rows) + exact f32 c2[n]
//   3) gemm_score: 128x128 tile bf16 MFMA; epilogue -> cand slots (no atomics)
//   4) finalize:  gmin over slot0s, filter 240 entries vs gmin+MARGIN,
//                 exact f64 rescore (~1-2 cols), masked gather.

#define M_TOTAL  8192
#define K_DIM    1024
#define N_REAL   5000
#define N_PAD    5120
#define NB_CNT   40          // N_PAD / 128
#define SLOTS    6           // slot0 = slice min, slots 1..5 = margin candidates
#define MARGIN   8.0f

typedef __attribute__((ext_vector_type(8))) short bf16x8;
typedef __attribute__((ext_vector_type(4))) float f32x4;
typedef unsigned long long u64;

__device__ __forceinline__ ushort f2bf(float x) {
  union { float f; uint32_t u; } v; v.f = x;
  uint32_t r = v.u + 0x7FFFu + ((v.u >> 16) & 1u);   // round-to-nearest-even
  return (ushort)(r >> 16);
}

__device__ __forceinline__ void async16(void* lds, const void* g) {
  __builtin_amdgcn_global_load_lds(
      (const __attribute__((address_space(1))) void*)g,
      (__attribute__((address_space(3))) void*)lds, 16, 0, 0);
}

// monotone float<->uint32 encode (total order matches float order)
__device__ __forceinline__ uint32_t fenc(float f) {
  union { float f; uint32_t u; } v; v.f = f;
  return v.u ^ ((v.u >> 31) ? 0xFFFFFFFFu : 0x80000000u);
}
__device__ __forceinline__ float fdec(uint32_t e) {
  uint32_t u = e ^ ((e & 0x80000000u) ? 0x80000000u : 0xFFFFFFFFu);
  union { uint32_t u; float f; } v; v.u = u; return v.f;
}

// ---------------------------------------------------------------- prep kernels

__global__ __launch_bounds__(256) void convert_z(const float4* __restrict__ z4,
                                                 ushort* __restrict__ zb, int n4) {
  int i = blockIdx.x * blockDim.x + threadIdx.x;
  int stride = gridDim.x * blockDim.x;
  for (; i < n4; i += stride) {
    float4 v = z4[i];
    ushort4 u;
    u.x = f2bf(v.x); u.y = f2bf(v.y); u.z = f2bf(v.z); u.w = f2bf(v.w);
    *(ushort4*)&zb[(size_t)i * 4] = u;
  }
}

__global__ __launch_bounds__(256) void prep_cb(const float* __restrict__ cb,
                                               ushort* __restrict__ cbb,
                                               float* __restrict__ c2) {
  __shared__ float sred[4];
  const int row = blockIdx.x;       // 0..5119
  const int tid = threadIdx.x;
  if (row >= N_REAL) {              // zero pad rows so GEMM reads are benign
    ushort4 zz; zz.x = zz.y = zz.z = zz.w = 0;
    *(ushort4*)&cbb[(size_t)row * K_DIM + tid * 4] = zz;
    if (tid == 0) c2[row] = 0.f;
    return;
  }
  float4 v = ((const float4*)(cb + (size_t)row * K_DIM))[tid];
  ushort4 u;
  u.x = f2bf(v.x); u.y = f2bf(v.y); u.z = f2bf(v.z); u.w = f2bf(v.w);
  *(ushort4*)&cbb[(size_t)row * K_DIM + tid * 4] = u;
  float s = v.x * v.x + v.y * v.y + v.z * v.z + v.w * v.w;
  #pragma unroll
  for (int off = 32; off; off >>= 1) s += __shfl_down(s, off);
  int wv = tid >> 6, ln = tid & 63;
  if (ln == 0) sred[wv] = s;
  __syncthreads();
  if (tid == 0) c2[row] = sred[0] + sred[1] + sred[2] + sred[3];
}

// ------------------------------------------------- GEMM + fused argmin/collect
// 128x128 tile, BK=64, 4 waves (2x2 of 64x64), 16x16x32 bf16 MFMA.
// A = z_bf16 [8192][1024], B = cb_bf16 [5120][1024] (both K-major -> C = A.B^T)

__global__ __launch_bounds__(256) void gemm_score(const ushort* __restrict__ A,
                                                  const ushort* __restrict__ Bm,
                                                  const float* __restrict__ c2,
                                                  u64* __restrict__ cand) {
  __shared__ __align__(16) char smem[32768];
  ushort* sA = (ushort*)smem;                       // 16 KB
  ushort* sB = (ushort*)(smem + 16384);             // 16 KB
  // epilogue reuses the same LDS (after a barrier):
  u64 (*scand)[SLOTS] = (u64 (*)[SLOTS])smem;       // 128*6*8 = 6144 B
  int* scnt = (int*)(smem + 6144);                  // 512 B

  const int tid  = threadIdx.x;
  const int wave = tid >> 6, lane = tid & 63;
  const int wm = wave >> 1, wn = wave & 1;
  const int tM = blockIdx.y * 128;             // A row
  const int tN = blockIdx.x * 128;             // codebook row
  const int nb = blockIdx.x;                   // N-slice id

  f32x4 acc[4][4];
  #pragma unroll
  for (int i = 0; i < 4; ++i)
    #pragma unroll
    for (int j = 0; j < 4; ++j)
      acc[i][j] = (f32x4)0.f;

  char* sAb = (char*)sA;
  char* sBb = (char*)sB;
  const int o = tid * 16;                      // byte offset within 16KB tile

  for (int k0 = 0; k0 < K_DIM; k0 += 64) {
    __syncthreads();                           // protect LDS from prev readers
    #pragma unroll
    for (int it = 0; it < 4; ++it) {
      int ob = o + it * 4096;                  // 0..16383
      int r  = ob >> 7;                        // tile row (128B per row)
      int cbyte = ob & 127;
      const char* ga = (const char*)A + ((size_t)(tM + r) * K_DIM + k0) * 2 + cbyte;
      async16(sAb + ob, ga);
      const char* gb = (const char*)Bm + ((size_t)(tN + r) * K_DIM + k0) * 2 + cbyte;
      async16(sBb + ob, gb);
    }
    __syncthreads();                           // drains vmcnt before barrier
    #pragma unroll
    for (int kk = 0; kk < 2; ++kk) {
      bf16x8 af[4], bfr[4];
      const int kcol = kk * 32 + (lane >> 4) * 8;
      #pragma unroll
      for (int f = 0; f < 4; ++f) {
        int ra = wm * 64 + f * 16 + (lane & 15);
        af[f]  = *(const bf16x8*)&sA[ra * 64 + kcol];
        int rb = wn * 64 + f * 16 + (lane & 15);
        bfr[f] = *(const bf16x8*)&sB[rb * 64 + kcol];
      }
      #pragma unroll
      for (int i = 0; i < 4; ++i)
        #pragma unroll
        for (int j = 0; j < 4; ++j)
          acc[i][j] = __builtin_amdgcn_mfma_f32_16x16x32_bf16(af[i], bfr[j], acc[i][j], 0, 0, 0);
    }
  }

  // ---- fused epilogue: block-local, LDS atomics only ----
  // C/D layout: row = i*16 + (lane>>4)*4 + r (in wave tile), col = j*16 + (lane&15)
  __syncthreads();                             // done reading sA/sB; reuse LDS
  if (tid < 128) {
    scnt[tid] = 0;
    #pragma unroll
    for (int s = 0; s < SLOTS; ++s) scand[tid][s] = ~0ull;
  }
  __syncthreads();

  const int cl = lane & 15, rg = lane >> 4;
  int   ncol[4];
  float c2v[4];
  #pragma unroll
  for (int j = 0; j < 4; ++j) {
    ncol[j] = tN + wn * 64 + j * 16 + cl;
    c2v[j]  = (ncol[j] < N_REAL) ? c2[ncol[j]] : 0.f;
  }

  // pass A: per-row lex-min over this wave's 64 cols -> LDS atomicMin (slot 0)
  #pragma unroll
  for (int i = 0; i < 4; ++i) {
    #pragma unroll
    for (int r = 0; r < 4; ++r) {
      float bv = 3.4e38f; int bc = 0x7fffffff;
      #pragma unroll
      for (int j = 0; j < 4; ++j) {
        float sc = (ncol[j] < N_REAL) ? (c2v[j] - 2.0f * acc[i][j][r]) : 3.4e38f;
        if (sc < bv || (sc == bv && ncol[j] < bc)) { bv = sc; bc = ncol[j]; }
      }
      #pragma unroll
      for (int off = 1; off < 16; off <<= 1) {   // stays within the rg group
        float ov = __shfl_xor(bv, off);
        int   oc = __shfl_xor(bc, off);
        if (ov < bv || (ov == bv && oc < bc)) { bv = ov; bc = oc; }
      }
      if (cl == 0) {
        const int lr = wm * 64 + i * 16 + rg * 4 + r;
        u64 pk = ((u64)fenc(bv) << 32) | (uint32_t)bc;
        atomicMin(&scand[lr][0], pk);
      }
    }
  }
  __syncthreads();

  // pass B: append margin candidates (excluding the slice-min col)
  #pragma unroll
  for (int i = 0; i < 4; ++i) {
    #pragma unroll
    for (int r = 0; r < 4; ++r) {
      const int lr = wm * 64 + i * 16 + rg * 4 + r;
      const u64 mn = scand[lr][0];
      const float thr  = fdec((uint32_t)(mn >> 32)) + MARGIN;
      const int mincol = (int)(mn & 0xFFFFFFFFu);
      #pragma unroll
      for (int j = 0; j < 4; ++j) {
        if (ncol[j] < N_REAL) {
          float sc = c2v[j] - 2.0f * acc[i][j][r];
          if (sc <= thr && ncol[j] != mincol) {
            int p = atomicAdd(&scnt[lr], 1);
            if (p < SLOTS - 1)
              scand[lr][1 + p] = ((u64)fenc(sc) << 32) | (uint32_t)ncol[j];
          }
        }
      }
    }
  }
  __syncthreads();

  // store out: 6 slots per (row, slice); empty slots decode to NaN -> filtered
  if (tid < 128) {
    const size_t base = ((size_t)(tM + tid) * NB_CNT + nb) * SLOTS;
    #pragma unroll
    for (int s = 0; s < SLOTS; ++s) cand[base + s] = scand[tid][s];
  }
}

// ------------------------------------------------------- finalize (per query)

__global__ __launch_bounds__(256) void finalize(const u64* __restrict__ cand,
                                                const float* __restrict__ z,
                                                const float* __restrict__ cb,
                                                const int* __restrict__ mask,
                                                float* __restrict__ out_q,
                                                float* __restrict__ out_i,
                                                float* __restrict__ out_loss) {
  __shared__ u64 swm[4];
  __shared__ float sthr;
  __shared__ int scols[64];
  __shared__ int scnt2;
  __shared__ double sdv[4];
  __shared__ double sbestd;
  __shared__ int    sbesti;

  const int tid = threadIdx.x;
  const int m   = blockIdx.x;
  const int wv = tid >> 6, ln = tid & 63;
  const u64* row = cand + (size_t)m * (NB_CNT * SLOTS);   // 240 entries

  const u64 e = (tid < NB_CNT * SLOTS) ? row[tid] : ~0ull;

  // gmin over slot-0 entries (u64 lex order == (score, col) order)
  u64 g = (tid < NB_CNT * SLOTS && (tid % SLOTS) == 0) ? e : ~0ull;
  #pragma unroll
  for (int off = 32; off; off >>= 1) {
    u64 o = __shfl_down(g, off);
    if (o < g) g = o;
  }
  if (ln == 0) swm[wv] = g;
  __syncthreads();
  if (tid == 0) {
    u64 gg = swm[0];
    for (int w = 1; w < 4; ++w) if (swm[w] < gg) gg = swm[w];
    sthr = fdec((uint32_t)(gg >> 32)) + MARGIN;
    scnt2 = 0;
  }
  __syncthreads();

  // survivors: entries within gmin+MARGIN (empty slots decode NaN -> false)
  if (tid < NB_CNT * SLOTS) {
    float sc = fdec((uint32_t)(e >> 32));
    if (sc <= sthr) {
      int p = atomicAdd(&scnt2, 1);
      if (p < 64) scols[p] = (int)(e & 0xFFFFFFFFu);
    }
  }
  __syncthreads();
  int nc = scnt2 < 64 ? scnt2 : 64;

  // exact f64 rescore: sum c*(c - 2z)
  if (tid == 0) { sbestd = 1e300; sbesti = 0x7fffffff; }
  __syncthreads();
  const float4 zv = ((const float4*)(z + (size_t)m * K_DIM))[tid];
  for (int c = 0; c < nc; ++c) {
    const int n = scols[c];
    float4 cv = ((const float4*)(cb + (size_t)n * K_DIM))[tid];
    double lsum = (double)cv.x * ((double)cv.x - 2.0 * (double)zv.x)
                + (double)cv.y * ((double)cv.y - 2.0 * (double)zv.y)
                + (double)cv.z * ((double)cv.z - 2.0 * (double)zv.z)
                + (double)cv.w * ((double)cv.w - 2.0 * (double)zv.w);
    #pragma unroll
    for (int off = 32; off; off >>= 1) lsum += __shfl_down(lsum, off);
    if (ln == 0) sdv[wv] = lsum;
    __syncthreads();
    if (tid == 0) {
      double s = sdv[0] + sdv[1] + sdv[2] + sdv[3];
      if (s < sbestd || (s == sbestd && n < sbesti)) { sbestd = s; sbesti = n; }
    }
    __syncthreads();
  }

  const int bidx = sbesti;
  if (tid == 0) out_i[m] = (float)bidx;
  const int mk = mask[m];
  float4 qz; qz.x = qz.y = qz.z = qz.w = 0.f;
  float4 src = ((const float4*)(cb + (size_t)bidx * K_DIM))[tid];
  ((float4*)(out_q + (size_t)m * K_DIM))[tid] = mk ? src : qz;
  if (m == 0 && tid == 0) *out_loss = 0.0f;
}

// -------------------------------------------------------------------- launcher

extern "C" void kernel_launch(void* const* d_in, const int* in_sizes, int n_in,
                              void* d_out, int out_size, void* d_ws, size_t ws_size,
                              hipStream_t stream) {
  const float* z    = (const float*)d_in[0];
  const int*   mask = (const int*)d_in[1];
  const float* cb   = (const float*)d_in[2];

  float* out      = (float*)d_out;
  float* out_q    = out;                                   // [8192][1024]
  float* out_i    = out + (size_t)M_TOTAL * K_DIM;         // [8192] (as float)
  float* out_loss = out_i + M_TOTAL;                       // [1]

  char* ws = (char*)d_ws;
  ushort* zb   = (ushort*)(ws);                            // 16,777,216 B
  ushort* cbb  = (ushort*)(ws + 16777216);                 // 10,485,760 B
  float*  c2   = (float*)(ws + 27262976);                  //     20,480 B
  u64*    cand = (u64*)(ws + 27283456);                    // 15,728,640 B  (total 43.0 MB)

  convert_z<<<2048, 256, 0, stream>>>((const float4*)z, zb, (M_TOTAL * K_DIM) / 4);
  prep_cb<<<N_PAD, 256, 0, stream>>>(cb, cbb, c2);

  dim3 g(N_PAD / 128, M_TOTAL / 128);
  gemm_score<<<g, 256, 0, stream>>>(zb, cbb, c2, cand);
  finalize<<<M_TOTAL, 256, 0, stream>>>(cand, z, cb, mask, out_q, out_i, out_loss);
}

// Round 8
// 297.402 us; speedup vs baseline: 1.6841x; 1.0497x over previous
//
#include <hip/hip_runtime.h>
#include <stdint.h>

// KmeansAudioQuantizer on MI355X (gfx950)
// B=8, L=1024, C=1024, N=5000.  M = B*L = 8192 queries.
//
// Round 6 kernel, 2nd unchanged resubmit (GPU-acquisition timeouts; never ran):
// GEMM geometry + overlap upgrade (epilogue scheme unchanged from R5,
// which passed with absmax 0.0):
//   - 256x256 tile, BK=64, 8 waves (2Mx4N), wave tile 128x64, acc[8][4]
//   - double-buffered LDS (2 x 64 KB) with minimum-2-phase prefetch:
//     issue next tile's global_load_lds BEFORE computing current tile,
//     one drain+barrier per K-step (m248 2ph pattern, ~655 TF @ K=1024)
//   - block-local epilogue: per-(row, 256-col slice) lex-min + margin
//     candidates via LDS atomics only -> cand[m][20][6] packed u64
//   - finalize: gmin over slot0s, filter 120 entries vs gmin+MARGIN,
//     exact f64 rescore (~1-2 cols), masked gather.

#define M_TOTAL  8192
#define K_DIM    1024
#define N_REAL   5000
#define N_PAD    5120
#define NB_CNT   20          // N_PAD / 256
#define SLOTS    6           // slot0 = slice min, slots 1..5 = margin candidates
#define MARGIN   8.0f

typedef __attribute__((ext_vector_type(8))) short bf16x8;
typedef __attribute__((ext_vector_type(4))) float f32x4;
typedef unsigned long long u64;

__device__ __forceinline__ ushort f2bf(float x) {
  union { float f; uint32_t u; } v; v.f = x;
  uint32_t r = v.u + 0x7FFFu + ((v.u >> 16) & 1u);   // round-to-nearest-even
  return (ushort)(r >> 16);
}

__device__ __forceinline__ void async16(void* lds, const void* g) {
  __builtin_amdgcn_global_load_lds(
      (const __attribute__((address_space(1))) void*)g,
      (__attribute__((address_space(3))) void*)lds, 16, 0, 0);
}

// monotone float<->uint32 encode (total order matches float order)
__device__ __forceinline__ uint32_t fenc(float f) {
  union { float f; uint32_t u; } v; v.f = f;
  return v.u ^ ((v.u >> 31) ? 0xFFFFFFFFu : 0x80000000u);
}
__device__ __forceinline__ float fdec(uint32_t e) {
  uint32_t u = e ^ ((e & 0x80000000u) ? 0x80000000u : 0xFFFFFFFFu);
  union { uint32_t u; float f; } v; v.u = u; return v.f;
}

// ---------------------------------------------------------------- prep kernels

__global__ __launch_bounds__(256) void convert_z(const float4* __restrict__ z4,
                                                 ushort* __restrict__ zb, int n4) {
  int i = blockIdx.x * blockDim.x + threadIdx.x;
  int stride = gridDim.x * blockDim.x;
  for (; i < n4; i += stride) {
    float4 v = z4[i];
    ushort4 u;
    u.x = f2bf(v.x); u.y = f2bf(v.y); u.z = f2bf(v.z); u.w = f2bf(v.w);
    *(ushort4*)&zb[(size_t)i * 4] = u;
  }
}

__global__ __launch_bounds__(256) void prep_cb(const float* __restrict__ cb,
                                               ushort* __restrict__ cbb,
                                               float* __restrict__ c2) {
  __shared__ float sred[4];
  const int row = blockIdx.x;       // 0..5119
  const int tid = threadIdx.x;
  if (row >= N_REAL) {              // zero pad rows so GEMM reads are benign
    ushort4 zz; zz.x = zz.y = zz.z = zz.w = 0;
    *(ushort4*)&cbb[(size_t)row * K_DIM + tid * 4] = zz;
    if (tid == 0) c2[row] = 0.f;
    return;
  }
  float4 v = ((const float4*)(cb + (size_t)row * K_DIM))[tid];
  ushort4 u;
  u.x = f2bf(v.x); u.y = f2bf(v.y); u.z = f2bf(v.z); u.w = f2bf(v.w);
  *(ushort4*)&cbb[(size_t)row * K_DIM + tid * 4] = u;
  float s = v.x * v.x + v.y * v.y + v.z * v.z + v.w * v.w;
  #pragma unroll
  for (int off = 32; off; off >>= 1) s += __shfl_down(s, off);
  int wv = tid >> 6, ln = tid & 63;
  if (ln == 0) sred[wv] = s;
  __syncthreads();
  if (tid == 0) c2[row] = sred[0] + sred[1] + sred[2] + sred[3];
}

// ------------------------------------------------- GEMM + fused argmin/collect
// 256x256 tile, BK=64, 8 waves (2x4 of 128x64), 16x16x32 bf16 MFMA,
// double-buffered LDS with prefetch-before-compute (2-phase).
// A = z_bf16 [8192][1024], B = cb_bf16 [5120][1024] (both K-major -> C = A.B^T)

__global__ __launch_bounds__(512) void gemm_score(const ushort* __restrict__ A,
                                                  const ushort* __restrict__ Bm,
                                                  const float* __restrict__ c2,
                                                  u64* __restrict__ cand) {
  __shared__ __align__(16) char smem[131072];
  // buffer b (0/1): A tile at b*65536 (32 KB, [256][64] ushort),
  //                 B tile at b*65536 + 32768 (32 KB)
  // epilogue overlay (after barrier): scand[256][6] u64 (12 KB) + scnt[256]

  const int tid  = threadIdx.x;
  const int wave = tid >> 6, lane = tid & 63;
  const int wm = wave >> 2, wn = wave & 3;     // 2 x 4 wave grid
  const int tM = blockIdx.y * 256;             // A row
  const int tN = blockIdx.x * 256;             // codebook row
  const int nb = blockIdx.x;                   // N-slice id

  f32x4 acc[8][4];
  #pragma unroll
  for (int i = 0; i < 8; ++i)
    #pragma unroll
    for (int j = 0; j < 4; ++j)
      acc[i][j] = (f32x4)0.f;

  const int o = tid * 16;                      // byte offset, 512 thr x 16B = 8 KB sweep

  // stage one 256x64 A-tile + B-tile into buffer b (8 x async16 per thread)
  auto stage = [&](int b, int k0) {
    char* dstA = smem + b * 65536;
    char* dstB = dstA + 32768;
    #pragma unroll
    for (int it = 0; it < 4; ++it) {
      int ob = o + it * 8192;                  // 0..32767
      int r  = ob >> 7;                        // tile row (128 B per row)
      int cbyte = ob & 127;
      async16(dstA + ob, (const char*)A  + ((size_t)(tM + r) * K_DIM + k0) * 2 + cbyte);
      async16(dstB + ob, (const char*)Bm + ((size_t)(tN + r) * K_DIM + k0) * 2 + cbyte);
    }
  };

  auto compute = [&](int b) {
    const ushort* sA = (const ushort*)(smem + b * 65536);
    const ushort* sB = (const ushort*)(smem + b * 65536 + 32768);
    #pragma unroll
    for (int kk = 0; kk < 2; ++kk) {
      const int kcol = kk * 32 + (lane >> 4) * 8;
      bf16x8 af[8], bfr[4];
      #pragma unroll
      for (int f = 0; f < 8; ++f)
        af[f] = *(const bf16x8*)&sA[(wm * 128 + f * 16 + (lane & 15)) * 64 + kcol];
      #pragma unroll
      for (int f = 0; f < 4; ++f)
        bfr[f] = *(const bf16x8*)&sB[(wn * 64 + f * 16 + (lane & 15)) * 64 + kcol];
      #pragma unroll
      for (int i = 0; i < 8; ++i)
        #pragma unroll
        for (int j = 0; j < 4; ++j)
          acc[i][j] = __builtin_amdgcn_mfma_f32_16x16x32_bf16(af[i], bfr[j], acc[i][j], 0, 0, 0);
    }
  };

  // 2-phase: prefetch next tile before computing current; one drain per step.
  stage(0, 0);
  __syncthreads();                             // drains vmcnt(0) before barrier
  int cur = 0;
  for (int t = 0; t < (K_DIM / 64) - 1; ++t) {
    stage(cur ^ 1, (t + 1) * 64);              // in flight during compute
    compute(cur);
    __syncthreads();                           // drain + barrier
    cur ^= 1;
  }
  compute(cur);

  // ---- fused epilogue: block-local, LDS atomics only ----
  // C/D layout: row = i*16 + (lane>>4)*4 + r (in wave tile), col = j*16 + (lane&15)
  __syncthreads();                             // done reading LDS; reuse it
  u64 (*scand)[SLOTS] = (u64 (*)[SLOTS])smem;  // 256*6*8 = 12288 B
  int* scnt = (int*)(smem + 12288);            // 1024 B
  if (tid < 256) {
    scnt[tid] = 0;
    #pragma unroll
    for (int s = 0; s < SLOTS; ++s) scand[tid][s] = ~0ull;
  }
  __syncthreads();

  const int cl = lane & 15, rg = lane >> 4;
  int   ncol[4];
  float c2v[4];
  #pragma unroll
  for (int j = 0; j < 4; ++j) {
    ncol[j] = tN + wn * 64 + j * 16 + cl;
    c2v[j]  = (ncol[j] < N_REAL) ? c2[ncol[j]] : 0.f;
  }

  // pass A: per-row lex-min over this wave's 64 cols -> LDS atomicMin (slot 0)
  #pragma unroll
  for (int i = 0; i < 8; ++i) {
    #pragma unroll
    for (int r = 0; r < 4; ++r) {
      float bv = 3.4e38f; int bc = 0x7fffffff;
      #pragma unroll
      for (int j = 0; j < 4; ++j) {
        float sc = (ncol[j] < N_REAL) ? (c2v[j] - 2.0f * acc[i][j][r]) : 3.4e38f;
        if (sc < bv || (sc == bv && ncol[j] < bc)) { bv = sc; bc = ncol[j]; }
      }
      #pragma unroll
      for (int off = 1; off < 16; off <<= 1) {   // stays within the rg group
        float ov = __shfl_xor(bv, off);
        int   oc = __shfl_xor(bc, off);
        if (ov < bv || (ov == bv && oc < bc)) { bv = ov; bc = oc; }
      }
      if (cl == 0) {
        const int lr = wm * 128 + i * 16 + rg * 4 + r;
        u64 pk = ((u64)fenc(bv) << 32) | (uint32_t)bc;
        atomicMin(&scand[lr][0], pk);
      }
    }
  }
  __syncthreads();

  // pass B: append margin candidates (excluding the slice-min col)
  #pragma unroll
  for (int i = 0; i < 8; ++i) {
    #pragma unroll
    for (int r = 0; r < 4; ++r) {
      const int lr = wm * 128 + i * 16 + rg * 4 + r;
      const u64 mn = scand[lr][0];
      const float thr  = fdec((uint32_t)(mn >> 32)) + MARGIN;
      const int mincol = (int)(mn & 0xFFFFFFFFu);
      #pragma unroll
      for (int j = 0; j < 4; ++j) {
        if (ncol[j] < N_REAL) {
          float sc = c2v[j] - 2.0f * acc[i][j][r];
          if (sc <= thr && ncol[j] != mincol) {
            int p = atomicAdd(&scnt[lr], 1);
            if (p < SLOTS - 1)
              scand[lr][1 + p] = ((u64)fenc(sc) << 32) | (uint32_t)ncol[j];
          }
        }
      }
    }
  }
  __syncthreads();

  // store out: 6 slots per (row, slice); empty slots decode to NaN -> filtered
  if (tid < 256) {
    const size_t base = ((size_t)(tM + tid) * NB_CNT + nb) * SLOTS;
    #pragma unroll
    for (int s = 0; s < SLOTS; ++s) cand[base + s] = scand[tid][s];
  }
}

// ------------------------------------------------------- finalize (per query)

__global__ __launch_bounds__(256) void finalize(const u64* __restrict__ cand,
                                                const float* __restrict__ z,
                                                const float* __restrict__ cb,
                                                const int* __restrict__ mask,
                                                float* __restrict__ out_q,
                                                float* __restrict__ out_i,
                                                float* __restrict__ out_loss) {
  __shared__ u64 swm[4];
  __shared__ float sthr;
  __shared__ int scols[64];
  __shared__ int scnt2;
  __shared__ double sdv[4];
  __shared__ double sbestd;
  __shared__ int    sbesti;

  const int tid = threadIdx.x;
  const int m   = blockIdx.x;
  const int wv = tid >> 6, ln = tid & 63;
  const u64* row = cand + (size_t)m * (NB_CNT * SLOTS);   // 120 entries

  const u64 e = (tid < NB_CNT * SLOTS) ? row[tid] : ~0ull;

  // gmin over slot-0 entries (u64 lex order == (score, col) order)
  u64 g = (tid < NB_CNT * SLOTS && (tid % SLOTS) == 0) ? e : ~0ull;
  #pragma unroll
  for (int off = 32; off; off >>= 1) {
    u64 o = __shfl_down(g, off);
    if (o < g) g = o;
  }
  if (ln == 0) swm[wv] = g;
  __syncthreads();
  if (tid == 0) {
    u64 gg = swm[0];
    for (int w = 1; w < 4; ++w) if (swm[w] < gg) gg = swm[w];
    sthr = fdec((uint32_t)(gg >> 32)) + MARGIN;
    scnt2 = 0;
  }
  __syncthreads();

  // survivors: entries within gmin+MARGIN (empty slots decode NaN -> false)
  if (tid < NB_CNT * SLOTS) {
    float sc = fdec((uint32_t)(e >> 32));
    if (sc <= sthr) {
      int p = atomicAdd(&scnt2, 1);
      if (p < 64) scols[p] = (int)(e & 0xFFFFFFFFu);
    }
  }
  __syncthreads();
  int nc = scnt2 < 64 ? scnt2 : 64;

  // exact f64 rescore: sum c*(c - 2z)
  if (tid == 0) { sbestd = 1e300; sbesti = 0x7fffffff; }
  __syncthreads();
  const float4 zv = ((const float4*)(z + (size_t)m * K_DIM))[tid];
  for (int c = 0; c < nc; ++c) {
    const int n = scols[c];
    float4 cv = ((const float4*)(cb + (size_t)n * K_DIM))[tid];
    double lsum = (double)cv.x * ((double)cv.x - 2.0 * (double)zv.x)
                + (double)cv.y * ((double)cv.y - 2.0 * (double)zv.y)
                + (double)cv.z * ((double)cv.z - 2.0 * (double)zv.z)
                + (double)cv.w * ((double)cv.w - 2.0 * (double)zv.w);
    #pragma unroll
    for (int off = 32; off; off >>= 1) lsum += __shfl_down(lsum, off);
    if (ln == 0) sdv[wv] = lsum;
    __syncthreads();
    if (tid == 0) {
      double s = sdv[0] + sdv[1] + sdv[2] + sdv[3];
      if (s < sbestd || (s == sbestd && n < sbesti)) { sbestd = s; sbesti = n; }
    }
    __syncthreads();
  }

  const int bidx = sbesti;
  if (tid == 0) out_i[m] = (float)bidx;
  const int mk = mask[m];
  float4 qz; qz.x = qz.y = qz.z = qz.w = 0.f;
  float4 src = ((const float4*)(cb + (size_t)bidx * K_DIM))[tid];
  ((float4*)(out_q + (size_t)m * K_DIM))[tid] = mk ? src : qz;
  if (m == 0 && tid == 0) *out_loss = 0.0f;
}

// -------------------------------------------------------------------- launcher

extern "C" void kernel_launch(void* const* d_in, const int* in_sizes, int n_in,
                              void* d_out, int out_size, void* d_ws, size_t ws_size,
                              hipStream_t stream) {
  const float* z    = (const float*)d_in[0];
  const int*   mask = (const int*)d_in[1];
  const float* cb   = (const float*)d_in[2];

  float* out      = (float*)d_out;
  float* out_q    = out;                                   // [8192][1024]
  float* out_i    = out + (size_t)M_TOTAL * K_DIM;         // [8192] (as float)
  float* out_loss = out_i + M_TOTAL;                       // [1]

  char* ws = (char*)d_ws;
  ushort* zb   = (ushort*)(ws);                            // 16,777,216 B
  ushort* cbb  = (ushort*)(ws + 16777216);                 // 10,485,760 B
  float*  c2   = (float*)(ws + 27262976);                  //     20,480 B
  u64*    cand = (u64*)(ws + 27283456);                    //  7,864,320 B  (total 35.1 MB)

  convert_z<<<2048, 256, 0, stream>>>((const float4*)z, zb, (M_TOTAL * K_DIM) / 4);
  prep_cb<<<N_PAD, 256, 0, stream>>>(cb, cbb, c2);

  dim3 g(N_PAD / 256, M_TOTAL / 256);
  gemm_score<<<g, 512, 0, stream>>>(zb, cbb, c2, cand);
  finalize<<<M_TOTAL, 256, 0, stream>>>(cand, z, cb, mask, out_q, out_i, out_loss);
}

// Round 9
// 281.342 us; speedup vs baseline: 1.7802x; 1.0571x over previous
//
#include <hip/hip_runtime.h>
#include <stdint.h>

// KmeansAudioQuantizer on MI355X (gfx950)
// B=8, L=1024, C=1024, N=5000.  M = B*L = 8192 queries.
//
// Round 9: 8-phase-style schedule on the 256x256 geometry (T2+T4+T5 bundle,
// regime-gated to land together per m218/m230/m252):
//   - per K-tile: 4 quadrant phases x 16 MFMA, setprio(1) around each cluster
//   - staging in 8 x 8KB quarter-chunks, 2 issued per phase, consume-ordered
//     (Bq0,Bq1,Bq2,Bq3,Aq0,Aq2,Aq1,Aq3) -> counted waits vmcnt(4)/vmcnt(6),
//     never drain-to-0 in the main loop; last tile peeled (vmcnt(2)/(0))
//   - LDS XOR swizzle byte^=((row&7)<<4): linear global_load_lds dest +
//     inverse-swizzled per-lane SOURCE + swizzled ds_read (both-sides rule)
//   - epilogue (block-local lex-min + margin candidates) unchanged from R8
//     (passed absmax 0.0); finalize/convert/prep unchanged.

#define M_TOTAL  8192
#define K_DIM    1024
#define N_REAL   5000
#define N_PAD    5120
#define NB_CNT   20          // N_PAD / 256
#define SLOTS    6           // slot0 = slice min, slots 1..5 = margin candidates
#define MARGIN   8.0f

typedef __attribute__((ext_vector_type(8))) short bf16x8;
typedef __attribute__((ext_vector_type(4))) float f32x4;
typedef unsigned long long u64;

__device__ __forceinline__ ushort f2bf(float x) {
  union { float f; uint32_t u; } v; v.f = x;
  uint32_t r = v.u + 0x7FFFu + ((v.u >> 16) & 1u);   // round-to-nearest-even
  return (ushort)(r >> 16);
}

__device__ __forceinline__ void async16(void* lds, const void* g) {
  __builtin_amdgcn_global_load_lds(
      (const __attribute__((address_space(1))) void*)g,
      (__attribute__((address_space(3))) void*)lds, 16, 0, 0);
}

// monotone float<->uint32 encode (total order matches float order)
__device__ __forceinline__ uint32_t fenc(float f) {
  union { float f; uint32_t u; } v; v.f = f;
  return v.u ^ ((v.u >> 31) ? 0xFFFFFFFFu : 0x80000000u);
}
__device__ __forceinline__ float fdec(uint32_t e) {
  uint32_t u = e ^ ((e & 0x80000000u) ? 0x80000000u : 0xFFFFFFFFu);
  union { uint32_t u; float f; } v; v.u = u; return v.f;
}

#define MFMA16(a, b, c) __builtin_amdgcn_mfma_f32_16x16x32_bf16((a), (b), (c), 0, 0, 0)

// ---------------------------------------------------------------- prep kernels

__global__ __launch_bounds__(256) void convert_z(const float4* __restrict__ z4,
                                                 ushort* __restrict__ zb, int n4) {
  int i = blockIdx.x * blockDim.x + threadIdx.x;
  int stride = gridDim.x * blockDim.x;
  for (; i < n4; i += stride) {
    float4 v = z4[i];
    ushort4 u;
    u.x = f2bf(v.x); u.y = f2bf(v.y); u.z = f2bf(v.z); u.w = f2bf(v.w);
    *(ushort4*)&zb[(size_t)i * 4] = u;
  }
}

__global__ __launch_bounds__(256) void prep_cb(const float* __restrict__ cb,
                                               ushort* __restrict__ cbb,
                                               float* __restrict__ c2) {
  __shared__ float sred[4];
  const int row = blockIdx.x;       // 0..5119
  const int tid = threadIdx.x;
  if (row >= N_REAL) {              // zero pad rows so GEMM reads are benign
    ushort4 zz; zz.x = zz.y = zz.z = zz.w = 0;
    *(ushort4*)&cbb[(size_t)row * K_DIM + tid * 4] = zz;
    if (tid == 0) c2[row] = 0.f;
    return;
  }
  float4 v = ((const float4*)(cb + (size_t)row * K_DIM))[tid];
  ushort4 u;
  u.x = f2bf(v.x); u.y = f2bf(v.y); u.z = f2bf(v.z); u.w = f2bf(v.w);
  *(ushort4*)&cbb[(size_t)row * K_DIM + tid * 4] = u;
  float s = v.x * v.x + v.y * v.y + v.z * v.z + v.w * v.w;
  #pragma unroll
  for (int off = 32; off; off >>= 1) s += __shfl_down(s, off);
  int wv = tid >> 6, ln = tid & 63;
  if (ln == 0) sred[wv] = s;
  __syncthreads();
  if (tid == 0) c2[row] = sred[0] + sred[1] + sred[2] + sred[3];
}

// ------------------------------------------------- GEMM + fused argmin/collect
// 256x256 tile, BK=64, 8 waves (2x4 of 128x64), 16x16x32 bf16 MFMA.
// A = z_bf16 [8192][1024], B = cb_bf16 [5120][1024] (both K-major -> C = A.B^T)
// Buffer b at smem + b*65536: A tile [256][64] @0 (32KB), B tile @32768.
// Swizzle: physical LDS byte = row*128 + (colbyte ^ ((row&7)<<4)).

__global__ __launch_bounds__(512, 2) void gemm_score(const ushort* __restrict__ A,
                                                     const ushort* __restrict__ Bm,
                                                     const float* __restrict__ c2,
                                                     u64* __restrict__ cand) {
  __shared__ __align__(16) char smem[131072];

  const int tid  = threadIdx.x;
  const int wave = tid >> 6, lane = tid & 63;
  const int wm = wave >> 2, wn = wave & 3;     // 2 x 4 wave grid
  const int tM = blockIdx.y * 256;
  const int tN = blockIdx.x * 256;
  const int nb = blockIdx.x;

  f32x4 acc[8][4];
  #pragma unroll
  for (int i = 0; i < 8; ++i)
    #pragma unroll
    for (int j = 0; j < 4; ++j)
      acc[i][j] = (f32x4)0.f;

  // staging constants: linear LDS dest, inverse-swizzled global source.
  // chunk = 64 rows x 64 cols (8KB); thread handles row tid>>3, 16B blk tid&7.
  const int srow = tid >> 3;                       // 0..63
  const int scol = ((tid & 7) ^ (srow & 7)) * 8;   // source element offset
  const int sdst = tid * 16;                       // linear dest byte in chunk

  // read constants (swizzled ds_read_b128)
  const int lrow = lane & 15;
  const int kgrp = (lane >> 4) * 16;               // byte col within row
  const int xorv = (lane & 7) << 4;

  auto stA = [&](int b, int q, int k0) {
    async16(smem + b * 65536 + q * 8192 + sdst,
            (const char*)A + ((size_t)(tM + q * 64 + srow) * K_DIM + k0 + scol) * 2);
  };
  auto stB = [&](int b, int q, int k0) {
    async16(smem + b * 65536 + 32768 + q * 8192 + sdst,
            (const char*)Bm + ((size_t)(tN + q * 64 + srow) * K_DIM + k0 + scol) * 2);
  };
  auto ldA = [&](int b, int i, int kk) {
    return *(const bf16x8*)(smem + b * 65536 +
           (wm * 128 + i * 16 + lrow) * 128 + ((kk * 64 + kgrp) ^ xorv));
  };
  auto ldB = [&](int b, int j, int kk) {
    return *(const bf16x8*)(smem + b * 65536 + 32768 +
           (wn * 64 + j * 16 + lrow) * 128 + ((kk * 64 + kgrp) ^ xorv));
  };

  bf16x8 aLo[4][2], aHi[4][2], bLo[2][2], bHi[2][2];

  // prologue: stage K-tile 0 into buf0, in consume order (8 chunks)
  stB(0,0,0); stB(0,1,0); stB(0,2,0); stB(0,3,0);
  stA(0,0,0); stA(0,2,0); stA(0,1,0); stA(0,3,0);

  for (int t = 0; t < (K_DIM / 64) - 1; ++t) {
    const int b = t & 1, nbf = b ^ 1;
    const int k1 = (t + 1) * 64;

    // -- P1: stage Bq0,Bq1(t+1) | vmcnt(4)->oldest 6 of tile t landed | barrier
    stB(nbf, 0, k1); stB(nbf, 1, k1);
    asm volatile("s_waitcnt vmcnt(4)" ::: "memory");
    __builtin_amdgcn_s_barrier();
    #pragma unroll
    for (int i = 0; i < 4; ++i) { aLo[i][0] = ldA(b,i,0); aLo[i][1] = ldA(b,i,1); }
    #pragma unroll
    for (int j = 0; j < 2; ++j) { bLo[j][0] = ldB(b,j,0); bLo[j][1] = ldB(b,j,1); }
    __builtin_amdgcn_s_setprio(1);
    #pragma unroll
    for (int i = 0; i < 4; ++i)
      #pragma unroll
      for (int j = 0; j < 2; ++j) {
        acc[i][j] = MFMA16(aLo[i][0], bLo[j][0], acc[i][j]);
        acc[i][j] = MFMA16(aLo[i][1], bLo[j][1], acc[i][j]);
      }
    __builtin_amdgcn_s_setprio(0);

    // -- P2: stage Bq2,Bq3 | read bHi | MFMA i0-3 x j2-3
    stB(nbf, 2, k1); stB(nbf, 3, k1);
    #pragma unroll
    for (int j = 0; j < 2; ++j) { bHi[j][0] = ldB(b,j+2,0); bHi[j][1] = ldB(b,j+2,1); }
    __builtin_amdgcn_s_setprio(1);
    #pragma unroll
    for (int i = 0; i < 4; ++i)
      #pragma unroll
      for (int j = 0; j < 2; ++j) {
        acc[i][j+2] = MFMA16(aLo[i][0], bHi[j][0], acc[i][j+2]);
        acc[i][j+2] = MFMA16(aLo[i][1], bHi[j][1], acc[i][j+2]);
      }
    __builtin_amdgcn_s_setprio(0);

    // -- P3: stage Aq0,Aq2 | vmcnt(6)->tile t's Aq1,Aq3 landed | barrier
    stA(nbf, 0, k1); stA(nbf, 2, k1);
    asm volatile("s_waitcnt vmcnt(6)" ::: "memory");
    __builtin_amdgcn_s_barrier();
    #pragma unroll
    for (int i = 0; i < 4; ++i) { aHi[i][0] = ldA(b,i+4,0); aHi[i][1] = ldA(b,i+4,1); }
    #pragma unroll
    for (int j = 0; j < 2; ++j) { bLo[j][0] = ldB(b,j,0); bLo[j][1] = ldB(b,j,1); }
    __builtin_amdgcn_s_setprio(1);
    #pragma unroll
    for (int i = 0; i < 4; ++i)
      #pragma unroll
      for (int j = 0; j < 2; ++j) {
        acc[i+4][j] = MFMA16(aHi[i][0], bLo[j][0], acc[i+4][j]);
        acc[i+4][j] = MFMA16(aHi[i][1], bLo[j][1], acc[i+4][j]);
      }
    __builtin_amdgcn_s_setprio(0);

    // -- P4: stage Aq1,Aq3 | re-read bHi | MFMA i4-7 x j2-3 | end-of-tile barrier
    stA(nbf, 1, k1); stA(nbf, 3, k1);
    #pragma unroll
    for (int j = 0; j < 2; ++j) { bHi[j][0] = ldB(b,j+2,0); bHi[j][1] = ldB(b,j+2,1); }
    __builtin_amdgcn_s_setprio(1);
    #pragma unroll
    for (int i = 0; i < 4; ++i)
      #pragma unroll
      for (int j = 0; j < 2; ++j) {
        acc[i+4][j+2] = MFMA16(aHi[i][0], bHi[j][0], acc[i+4][j+2]);
        acc[i+4][j+2] = MFMA16(aHi[i][1], bHi[j][1], acc[i+4][j+2]);
      }
    __builtin_amdgcn_s_setprio(0);
    __builtin_amdgcn_s_barrier();
  }

  // ---- peeled final tile (t = 15, buf1): no staging; counted then full drain
  {
    const int b = 1;
    asm volatile("s_waitcnt vmcnt(2)" ::: "memory");
    __builtin_amdgcn_s_barrier();
    #pragma unroll
    for (int i = 0; i < 4; ++i) { aLo[i][0] = ldA(b,i,0); aLo[i][1] = ldA(b,i,1); }
    #pragma unroll
    for (int j = 0; j < 2; ++j) { bLo[j][0] = ldB(b,j,0); bLo[j][1] = ldB(b,j,1); }
    #pragma unroll
    for (int i = 0; i < 4; ++i)
      #pragma unroll
      for (int j = 0; j < 2; ++j) {
        acc[i][j] = MFMA16(aLo[i][0], bLo[j][0], acc[i][j]);
        acc[i][j] = MFMA16(aLo[i][1], bLo[j][1], acc[i][j]);
      }
    #pragma unroll
    for (int j = 0; j < 2; ++j) { bHi[j][0] = ldB(b,j+2,0); bHi[j][1] = ldB(b,j+2,1); }
    #pragma unroll
    for (int i = 0; i < 4; ++i)
      #pragma unroll
      for (int j = 0; j < 2; ++j) {
        acc[i][j+2] = MFMA16(aLo[i][0], bHi[j][0], acc[i][j+2]);
        acc[i][j+2] = MFMA16(aLo[i][1], bHi[j][1], acc[i][j+2]);
      }
    asm volatile("s_waitcnt vmcnt(0)" ::: "memory");
    __builtin_amdgcn_s_barrier();
    #pragma unroll
    for (int i = 0; i < 4; ++i) { aHi[i][0] = ldA(b,i+4,0); aHi[i][1] = ldA(b,i+4,1); }
    #pragma unroll
    for (int i = 0; i < 4; ++i)
      #pragma unroll
      for (int j = 0; j < 2; ++j) {
        acc[i+4][j] = MFMA16(aHi[i][0], bLo[j][0], acc[i+4][j]);
        acc[i+4][j] = MFMA16(aHi[i][1], bLo[j][1], acc[i+4][j]);
        acc[i+4][j+2] = MFMA16(aHi[i][0], bHi[j][0], acc[i+4][j+2]);
        acc[i+4][j+2] = MFMA16(aHi[i][1], bHi[j][1], acc[i+4][j+2]);
      }
  }

  // ---- fused epilogue: block-local, LDS atomics only (unchanged from R8) ----
  // C/D layout: row = i*16 + (lane>>4)*4 + r (in wave tile), col = j*16 + (lane&15)
  __syncthreads();                             // full drain; reuse LDS
  u64 (*scand)[SLOTS] = (u64 (*)[SLOTS])smem;  // 256*6*8 = 12288 B
  int* scnt = (int*)(smem + 12288);            // 1024 B
  if (tid < 256) {
    scnt[tid] = 0;
    #pragma unroll
    for (int s = 0; s < SLOTS; ++s) scand[tid][s] = ~0ull;
  }
  __syncthreads();

  const int cl = lane & 15, rg = lane >> 4;
  int   ncol[4];
  float c2v[4];
  #pragma unroll
  for (int j = 0; j < 4; ++j) {
    ncol[j] = tN + wn * 64 + j * 16 + cl;
    c2v[j]  = (ncol[j] < N_REAL) ? c2[ncol[j]] : 0.f;
  }

  // pass A: per-row lex-min over this wave's 64 cols -> LDS atomicMin (slot 0)
  #pragma unroll
  for (int i = 0; i < 8; ++i) {
    #pragma unroll
    for (int r = 0; r < 4; ++r) {
      float bv = 3.4e38f; int bc = 0x7fffffff;
      #pragma unroll
      for (int j = 0; j < 4; ++j) {
        float sc = (ncol[j] < N_REAL) ? (c2v[j] - 2.0f * acc[i][j][r]) : 3.4e38f;
        if (sc < bv || (sc == bv && ncol[j] < bc)) { bv = sc; bc = ncol[j]; }
      }
      #pragma unroll
      for (int off = 1; off < 16; off <<= 1) {   // stays within the rg group
        float ov = __shfl_xor(bv, off);
        int   oc = __shfl_xor(bc, off);
        if (ov < bv || (ov == bv && oc < bc)) { bv = ov; bc = oc; }
      }
      if (cl == 0) {
        const int lr = wm * 128 + i * 16 + rg * 4 + r;
        u64 pk = ((u64)fenc(bv) << 32) | (uint32_t)bc;
        atomicMin(&scand[lr][0], pk);
      }
    }
  }
  __syncthreads();

  // pass B: append margin candidates (excluding the slice-min col)
  #pragma unroll
  for (int i = 0; i < 8; ++i) {
    #pragma unroll
    for (int r = 0; r < 4; ++r) {
      const int lr = wm * 128 + i * 16 + rg * 4 + r;
      const u64 mn = scand[lr][0];
      const float thr  = fdec((uint32_t)(mn >> 32)) + MARGIN;
      const int mincol = (int)(mn & 0xFFFFFFFFu);
      #pragma unroll
      for (int j = 0; j < 4; ++j) {
        if (ncol[j] < N_REAL) {
          float sc = c2v[j] - 2.0f * acc[i][j][r];
          if (sc <= thr && ncol[j] != mincol) {
            int p = atomicAdd(&scnt[lr], 1);
            if (p < SLOTS - 1)
              scand[lr][1 + p] = ((u64)fenc(sc) << 32) | (uint32_t)ncol[j];
          }
        }
      }
    }
  }
  __syncthreads();

  // store out: 6 slots per (row, slice); empty slots decode to NaN -> filtered
  if (tid < 256) {
    const size_t base = ((size_t)(tM + tid) * NB_CNT + nb) * SLOTS;
    #pragma unroll
    for (int s = 0; s < SLOTS; ++s) cand[base + s] = scand[tid][s];
  }
}

// ------------------------------------------------------- finalize (per query)

__global__ __launch_bounds__(256) void finalize(const u64* __restrict__ cand,
                                                const float* __restrict__ z,
                                                const float* __restrict__ cb,
                                                const int* __restrict__ mask,
                                                float* __restrict__ out_q,
                                                float* __restrict__ out_i,
                                                float* __restrict__ out_loss) {
  __shared__ u64 swm[4];
  __shared__ float sthr;
  __shared__ int scols[64];
  __shared__ int scnt2;
  __shared__ double sdv[4];
  __shared__ double sbestd;
  __shared__ int    sbesti;

  const int tid = threadIdx.x;
  const int m   = blockIdx.x;
  const int wv = tid >> 6, ln = tid & 63;
  const u64* row = cand + (size_t)m * (NB_CNT * SLOTS);   // 120 entries

  const u64 e = (tid < NB_CNT * SLOTS) ? row[tid] : ~0ull;

  // gmin over slot-0 entries (u64 lex order == (score, col) order)
  u64 g = (tid < NB_CNT * SLOTS && (tid % SLOTS) == 0) ? e : ~0ull;
  #pragma unroll
  for (int off = 32; off; off >>= 1) {
    u64 o = __shfl_down(g, off);
    if (o < g) g = o;
  }
  if (ln == 0) swm[wv] = g;
  __syncthreads();
  if (tid == 0) {
    u64 gg = swm[0];
    for (int w = 1; w < 4; ++w) if (swm[w] < gg) gg = swm[w];
    sthr = fdec((uint32_t)(gg >> 32)) + MARGIN;
    scnt2 = 0;
  }
  __syncthreads();

  // survivors: entries within gmin+MARGIN (empty slots decode NaN -> false)
  if (tid < NB_CNT * SLOTS) {
    float sc = fdec((uint32_t)(e >> 32));
    if (sc <= sthr) {
      int p = atomicAdd(&scnt2, 1);
      if (p < 64) scols[p] = (int)(e & 0xFFFFFFFFu);
    }
  }
  __syncthreads();
  int nc = scnt2 < 64 ? scnt2 : 64;

  // exact f64 rescore: sum c*(c - 2z)
  if (tid == 0) { sbestd = 1e300; sbesti = 0x7fffffff; }
  __syncthreads();
  const float4 zv = ((const float4*)(z + (size_t)m * K_DIM))[tid];
  for (int c = 0; c < nc; ++c) {
    const int n = scols[c];
    float4 cv = ((const float4*)(cb + (size_t)n * K_DIM))[tid];
    double lsum = (double)cv.x * ((double)cv.x - 2.0 * (double)zv.x)
                + (double)cv.y * ((double)cv.y - 2.0 * (double)zv.y)
                + (double)cv.z * ((double)cv.z - 2.0 * (double)zv.z)
                + (double)cv.w * ((double)cv.w - 2.0 * (double)zv.w);
    #pragma unroll
    for (int off = 32; off; off >>= 1) lsum += __shfl_down(lsum, off);
    if (ln == 0) sdv[wv] = lsum;
    __syncthreads();
    if (tid == 0) {
      double s = sdv[0] + sdv[1] + sdv[2] + sdv[3];
      if (s < sbestd || (s == sbestd && n < sbesti)) { sbestd = s; sbesti = n; }
    }
    __syncthreads();
  }

  const int bidx = sbesti;
  if (tid == 0) out_i[m] = (float)bidx;
  const int mk = mask[m];
  float4 qz; qz.x = qz.y = qz.z = qz.w = 0.f;
  float4 src = ((const float4*)(cb + (size_t)bidx * K_DIM))[tid];
  ((float4*)(out_q + (size_t)m * K_DIM))[tid] = mk ? src : qz;
  if (m == 0 && tid == 0) *out_loss = 0.0f;
}

// -------------------------------------------------------------------- launcher

extern "C" void kernel_launch(void* const* d_in, const int* in_sizes, int n_in,
                              void* d_out, int out_size, void* d_ws, size_t ws_size,
                              hipStream_t stream) {
  const float* z    = (const float*)d_in[0];
  const int*   mask = (const int*)d_in[1];
  const float* cb   = (const float*)d_in[2];

  float* out      = (float*)d_out;
  float* out_q    = out;                                   // [8192][1024]
  float* out_i    = out + (size_t)M_TOTAL * K_DIM;         // [8192] (as float)
  float* out_loss = out_i + M_TOTAL;                       // [1]

  char* ws = (char*)d_ws;
  ushort* zb   = (ushort*)(ws);                            // 16,777,216 B
  ushort* cbb  = (ushort*)(ws + 16777216);                 // 10,485,760 B
  float*  c2   = (float*)(ws + 27262976);                  //     20,480 B
  u64*    cand = (u64*)(ws + 27283456);                    //  7,864,320 B  (total 35.1 MB)

  convert_z<<<2048, 256, 0, stream>>>((const float4*)z, zb, (M_TOTAL * K_DIM) / 4);
  prep_cb<<<N_PAD, 256, 0, stream>>>(cb, cbb, c2);

  dim3 g(N_PAD / 256, M_TOTAL / 256);
  gemm_score<<<g, 512, 0, stream>>>(zb, cbb, c2, cand);
  finalize<<<M_TOTAL, 256, 0, stream>>>(cand, z, cb, mask, out_q, out_i, out_loss);
}